// Round 1
// baseline (977.105 us; speedup 1.0000x reference)
//
#include <hip/hip_runtime.h>
#include <hip/hip_bf16.h>
#include <stdint.h>

// Problem constants
#define DD 1024
#define AA 128
#define HH 8
#define FF 4096
#define BB 4
#define SS 2048
#define MM (BB*SS)      // 8192 tokens
#define EPSV 1e-5f

typedef __bf16 bf16x8 __attribute__((ext_vector_type(8)));
typedef __bf16 bf16x4 __attribute__((ext_vector_type(4)));
typedef float  f32x4  __attribute__((ext_vector_type(4)));

// ---------------- async global->LDS (16B per lane) ----------------
__device__ __forceinline__ void gload_lds16(const void* g, void* l) {
  __builtin_amdgcn_global_load_lds(
      (const __attribute__((address_space(1))) uint32_t*)(uintptr_t)g,
      (__attribute__((address_space(3))) uint32_t*)(uintptr_t)l, 16, 0, 0);
}

// ---------------- transpose + f32->bf16 convert: out[c][r] = in[r][c] ----------------
__global__ __launch_bounds__(256) void transpose_conv(const float* __restrict__ in,
                                                      __bf16* __restrict__ out,
                                                      int rows, int cols) {
  __shared__ float tile[64][65];
  const int r0 = blockIdx.y * 64, c0 = blockIdx.x * 64;
  for (int i = threadIdx.x; i < 4096; i += 256) {
    int r = i >> 6, c = i & 63;
    tile[r][c] = in[(long)(r0 + r) * cols + c0 + c];
  }
  __syncthreads();
  for (int i = threadIdx.x; i < 4096; i += 256) {
    int c = i >> 6, r = i & 63;
    out[(long)(c0 + c) * rows + r0 + r] = (__bf16)tile[r][c];
  }
}

// QKV weights: Wq/Wk/Wv are [H][D][A]; build WqkvT [3072][1024] (row n = p*1024+h*128+a, col d)
__global__ __launch_bounds__(256) void transpose_qkv(const float* __restrict__ Wq,
                                                     const float* __restrict__ Wk,
                                                     const float* __restrict__ Wv,
                                                     __bf16* __restrict__ out) {
  __shared__ float tile[64][65];
  const int z = blockIdx.z;
  const int p = z >> 3, h = z & 7;
  const float* in = ((p == 0) ? Wq : (p == 1) ? Wk : Wv) + (long)h * DD * AA;  // [D][A]
  __bf16* o = out + (long)(p * 1024 + h * 128) * DD;                           // [A][D]
  const int r0 = blockIdx.y * 64, c0 = blockIdx.x * 64;  // r over D, c over A
  for (int i = threadIdx.x; i < 4096; i += 256) {
    int r = i >> 6, c = i & 63;
    tile[r][c] = in[(long)(r0 + r) * AA + c0 + c];
  }
  __syncthreads();
  for (int i = threadIdx.x; i < 4096; i += 256) {
    int c = i >> 6, r = i & 63;
    o[(long)(c0 + c) * DD + r0 + r] = (__bf16)tile[r][c];
  }
}

__global__ void build_qkv_bias(const float* __restrict__ bq, const float* __restrict__ bk,
                               const float* __restrict__ bv, float* __restrict__ out) {
  int i = blockIdx.x * 256 + threadIdx.x;
  if (i < 3072) {
    const float* src = (i < 1024) ? bq : (i < 2048) ? bk : bv;
    out[i] = src[i & 1023];
  }
}

__global__ void conv_f32_bf16(const float* __restrict__ in, __bf16* __restrict__ out, int n4) {
  int i = blockIdx.x * 256 + threadIdx.x;
  if (i < n4) {
    float4 v = ((const float4*)in)[i];
    bf16x4 o = { (__bf16)v.x, (__bf16)v.y, (__bf16)v.z, (__bf16)v.w };
    ((bf16x4*)out)[i] = o;
  }
}

// ---------------- generic GEMM: C[M][N] = A[M][K](bf16) * Bt[N][K]^T + bias ----------------
// m97 structure: 128x128 tile, BK=32, 4 waves (2x2 of 64x64), 16x16x32 bf16 MFMA,
// global_load_lds width 16 staging, 2 barriers per K-step.
template<bool RELU, bool RESID, bool OUTF, bool OUTB, bool WRVT>
__global__ __launch_bounds__(256) void gemm_bt(
    const __bf16* __restrict__ Ag, const __bf16* __restrict__ Bt,
    const float* __restrict__ bias, const float* __restrict__ resid,
    float* __restrict__ Cf, __bf16* __restrict__ Cb, __bf16* __restrict__ vTb,
    int M, int N, int K)
{
  __shared__ __bf16 As[128 * 32];
  __shared__ __bf16 Bs[128 * 32];
  const int t = threadIdx.x;
  const int w = t >> 6, l = t & 63;
  const int m0 = blockIdx.y * 128, n0 = blockIdx.x * 128;
  const int wr = w >> 1, wc = w & 1;
  const int lr = l & 15, lg = l >> 4;

  f32x4 acc[4][4] = {};

  // staging: wave w covers 32 rows (2 issues of 16 rows); lane l -> row +(l>>2), col (l&3)*8
  const __bf16* gA = Ag + (long)(m0 + w * 32 + (l >> 2)) * K + (l & 3) * 8;
  const __bf16* gB = Bt + (long)(n0 + w * 32 + (l >> 2)) * K + (l & 3) * 8;
  __bf16* lA = &As[w * 1024];
  __bf16* lB = &Bs[w * 1024];

  for (int k0 = 0; k0 < K; k0 += 32) {
    gload_lds16(gA + k0, lA);
    gload_lds16(gA + (long)16 * K + k0, lA + 512);
    gload_lds16(gB + k0, lB);
    gload_lds16(gB + (long)16 * K + k0, lB + 512);
    __syncthreads();
    bf16x8 af[4], bfr[4];
#pragma unroll
    for (int mi = 0; mi < 4; mi++)
      af[mi] = *(const bf16x8*)&As[(wr * 64 + mi * 16 + lr) * 32 + lg * 8];
#pragma unroll
    for (int nj = 0; nj < 4; nj++)
      bfr[nj] = *(const bf16x8*)&Bs[(wc * 64 + nj * 16 + lr) * 32 + lg * 8];
#pragma unroll
    for (int mi = 0; mi < 4; mi++)
#pragma unroll
      for (int nj = 0; nj < 4; nj++)
        acc[mi][nj] = __builtin_amdgcn_mfma_f32_16x16x32_bf16(af[mi], bfr[nj], acc[mi][nj], 0, 0, 0);
    __syncthreads();
  }

#pragma unroll
  for (int mi = 0; mi < 4; mi++) {
    const int row0 = m0 + wr * 64 + mi * 16 + lg * 4;
#pragma unroll
    for (int nj = 0; nj < 4; nj++) {
      const int col = n0 + wc * 64 + nj * 16 + lr;
      const float bv = bias[col];
#pragma unroll
      for (int rg = 0; rg < 4; rg++) {
        const int row = row0 + rg;
        float v = acc[mi][nj][rg] + bv;
        if constexpr (RESID) v += resid[(long)row * N + col];
        if constexpr (RELU)  v = fmaxf(v, 0.f);
        if constexpr (OUTF)  Cf[(long)row * N + col] = v;
        if constexpr (OUTB)  Cb[(long)row * N + col] = (__bf16)v;
        if constexpr (WRVT) {
          if (col >= 2048) {  // V part -> also write V^T [b*8+h][a][s]
            int h = (col - 2048) >> 7, a = col & 127;
            int b = row >> 11, s = row & 2047;
            vTb[(((long)(b * 8 + h)) * 128 + a) * 2048 + s] = (__bf16)v;
          }
        }
      }
    }
  }
}

// ---------------- flash attention, heads summed ----------------
// grid (S/64, H, B); 4 waves, each owns 16 q-rows; KV tile = 128.
__global__ __launch_bounds__(256) void attn_kernel(
    const __bf16* __restrict__ qkv,   // [8192][3072]  (q | k | v per head)
    const __bf16* __restrict__ vT,    // [B*H*128][2048]
    float* __restrict__ hs)           // [8192][128] fp32, atomic head-sum
{
  __shared__ __bf16 P_lds[4 * 16 * 128];
  const int t = threadIdx.x, w = t >> 6, l = t & 63;
  const int lr = l & 15, lg = l >> 4;
  const int qt = blockIdx.x, h = blockIdx.y, b = blockIdx.z;
  const int q0 = qt * 64 + w * 16;
  const long rowbase = (long)b * SS + q0;
  const float inv_s = 0.0883883476483184f;  // 1/sqrt(128)

  // Q fragments: A[m=lr][k contiguous]
  bf16x8 qf[4];
  const __bf16* qptr = qkv + (rowbase + lr) * 3072 + h * 128;
#pragma unroll
  for (int ks = 0; ks < 4; ks++) qf[ks] = *(const bf16x8*)(qptr + ks * 32 + lg * 8);

  float m_[4] = { -1e30f, -1e30f, -1e30f, -1e30f };
  float l_[4] = {};
  f32x4 O[8] = {};

  __bf16* pl = &P_lds[w * 2048];
  const __bf16* kbase = qkv + (long)b * SS * 3072 + 1024 + h * 128;
  const __bf16* vbase = vT + ((long)(b * 8 + h) * 128) * 2048;

  for (int kt = 0; kt < SS / 128; kt++) {
    const int kv0 = kt * 128;
    f32x4 sc[8] = {};
    // QK^T: B-frag = K[kk][a-contig]
#pragma unroll
    for (int nj = 0; nj < 8; nj++) {
#pragma unroll
      for (int ks = 0; ks < 4; ks++) {
        bf16x8 kf = *(const bf16x8*)(kbase + (long)(kv0 + nj * 16 + lr) * 3072 + ks * 32 + lg * 8);
        sc[nj] = __builtin_amdgcn_mfma_f32_16x16x32_bf16(qf[ks], kf, sc[nj], 0, 0, 0);
      }
    }
    // scale + row max (rows live in regs rg, 16 lanes per row-group)
    float rmax[4] = { -1e30f, -1e30f, -1e30f, -1e30f };
#pragma unroll
    for (int nj = 0; nj < 8; nj++)
#pragma unroll
      for (int rg = 0; rg < 4; rg++) {
        float v = sc[nj][rg] * inv_s;
        sc[nj][rg] = v;
        rmax[rg] = fmaxf(rmax[rg], v);
      }
#pragma unroll
    for (int rg = 0; rg < 4; rg++)
#pragma unroll
      for (int d = 1; d < 16; d <<= 1) rmax[rg] = fmaxf(rmax[rg], __shfl_xor(rmax[rg], d));

    float ss[4], rsum[4];
#pragma unroll
    for (int rg = 0; rg < 4; rg++) {
      float nm = fmaxf(m_[rg], rmax[rg]);
      ss[rg] = __expf(m_[rg] - nm);
      m_[rg] = nm;
      rsum[rg] = 0.f;
    }
#pragma unroll
    for (int nj = 0; nj < 8; nj++)
#pragma unroll
      for (int rg = 0; rg < 4; rg++) {
        float p = __expf(sc[nj][rg] - m_[rg]);
        sc[nj][rg] = p;
        rsum[rg] += p;
      }
#pragma unroll
    for (int rg = 0; rg < 4; rg++) {
#pragma unroll
      for (int d = 1; d < 16; d <<= 1) rsum[rg] += __shfl_xor(rsum[rg], d);
      l_[rg] = l_[rg] * ss[rg] + rsum[rg];
    }
    f32x4 sv = { ss[0], ss[1], ss[2], ss[3] };
#pragma unroll
    for (int aj = 0; aj < 8; aj++) O[aj] *= sv;

    // P (exp'd scores) -> per-wave LDS as bf16, row = lg*4+rg, col = nj*16+lr
    asm volatile("s_waitcnt lgkmcnt(0)" ::: "memory");  // prior PV reads done before overwrite
#pragma unroll
    for (int nj = 0; nj < 8; nj++)
#pragma unroll
      for (int rg = 0; rg < 4; rg++)
        pl[(lg * 4 + rg) * 128 + nj * 16 + lr] = (__bf16)sc[nj][rg];
    asm volatile("s_waitcnt lgkmcnt(0)" ::: "memory");  // writes visible to whole wave

    // PV: A-frag = P[lr][kk-contig]; B-frag = vT[a][kk-contig]
#pragma unroll
    for (int ks = 0; ks < 4; ks++) {
      bf16x8 pa = *(const bf16x8*)(pl + lr * 128 + ks * 32 + lg * 8);
#pragma unroll
      for (int aj = 0; aj < 8; aj++) {
        bf16x8 vf = *(const bf16x8*)(vbase + (long)(aj * 16 + lr) * 2048 + kv0 + ks * 32 + lg * 8);
        O[aj] = __builtin_amdgcn_mfma_f32_16x16x32_bf16(pa, vf, O[aj], 0, 0, 0);
      }
    }
  }

  float invl[4];
#pragma unroll
  for (int rg = 0; rg < 4; rg++) invl[rg] = 1.f / l_[rg];
#pragma unroll
  for (int aj = 0; aj < 8; aj++)
#pragma unroll
    for (int rg = 0; rg < 4; rg++)
      atomicAdd(hs + (rowbase + lg * 4 + rg) * 128 + aj * 16 + lr, O[aj][rg] * invl[rg]);
}

// ---------------- LayerNorm over D=1024 (one block per row) ----------------
template<bool WB>
__global__ __launch_bounds__(256) void ln_kernel(
    const float* __restrict__ in, const float* __restrict__ g, const float* __restrict__ be,
    float* __restrict__ outf, __bf16* __restrict__ outb)
{
  const int row = blockIdx.x, t = threadIdx.x;
  const float4 xv = *(const float4*)(in + (long)row * DD + t * 4);
  float s = xv.x + xv.y + xv.z + xv.w;
  float s2 = xv.x * xv.x + xv.y * xv.y + xv.z * xv.z + xv.w * xv.w;
#pragma unroll
  for (int off = 32; off >= 1; off >>= 1) {
    s += __shfl_down(s, off);
    s2 += __shfl_down(s2, off);
  }
  __shared__ float sm[4], sm2[4];
  __shared__ float mu_s, rs_s;
  const int wid = t >> 6;
  if ((t & 63) == 0) { sm[wid] = s; sm2[wid] = s2; }
  __syncthreads();
  if (t == 0) {
    float S = sm[0] + sm[1] + sm[2] + sm[3];
    float S2 = sm2[0] + sm2[1] + sm2[2] + sm2[3];
    float mu = S * (1.f / 1024.f);
    float var = S2 * (1.f / 1024.f) - mu * mu;
    mu_s = mu;
    rs_s = rsqrtf(var + EPSV);
  }
  __syncthreads();
  const float mu = mu_s, rs = rs_s;
  const float4 gv = *(const float4*)(g + t * 4);
  const float4 bv = *(const float4*)(be + t * 4);
  float o0 = (xv.x - mu) * rs * gv.x + bv.x;
  float o1 = (xv.y - mu) * rs * gv.y + bv.y;
  float o2 = (xv.z - mu) * rs * gv.z + bv.z;
  float o3 = (xv.w - mu) * rs * gv.w + bv.w;
  float4 ov = { o0, o1, o2, o3 };
  *(float4*)(outf + (long)row * DD + t * 4) = ov;
  if constexpr (WB) {
    bf16x4 ob = { (__bf16)o0, (__bf16)o1, (__bf16)o2, (__bf16)o3 };
    *(bf16x4*)(outb + (long)row * DD + t * 4) = ob;
  }
}

// ---------------- launch ----------------
extern "C" void kernel_launch(void* const* d_in, const int* in_sizes, int n_in,
                              void* d_out, int out_size, void* d_ws, size_t ws_size,
                              hipStream_t stream) {
  const float* x    = (const float*)d_in[0];
  const float* Wq   = (const float*)d_in[1];
  const float* bq   = (const float*)d_in[2];
  const float* Wk   = (const float*)d_in[3];
  const float* bk   = (const float*)d_in[4];
  const float* Wv   = (const float*)d_in[5];
  const float* bv   = (const float*)d_in[6];
  const float* Wo   = (const float*)d_in[7];
  const float* bo   = (const float*)d_in[8];
  const float* g1   = (const float*)d_in[9];
  const float* be1  = (const float*)d_in[10];
  const float* g2   = (const float*)d_in[11];
  const float* be2  = (const float*)d_in[12];
  const float* W1   = (const float*)d_in[13];
  const float* bf1  = (const float*)d_in[14];
  const float* W2   = (const float*)d_in[15];
  const float* bf2  = (const float*)d_in[16];

  const size_t MB = 1ull << 20;
  char* ws = (char*)d_ws;
  __bf16* WqkvT    = (__bf16*)(ws + 0);        // 6 MB   [3072][1024]
  float*  qkv_bias = (float*) (ws + 6 * MB);   // 12 KB
  __bf16* WoT      = (__bf16*)(ws + 7 * MB);   // 256 KB [1024][128]
  __bf16* W1T      = (__bf16*)(ws + 8 * MB);   // 8 MB   [4096][1024]
  __bf16* W2T      = (__bf16*)(ws + 16 * MB);  // 8 MB   [1024][4096]
  __bf16* xb       = (__bf16*)(ws + 24 * MB);  // 16 MB  [8192][1024]
  __bf16* qkvb     = (__bf16*)(ws + 40 * MB);  // 48 MB  [8192][3072]
  __bf16* vTb      = (__bf16*)(ws + 88 * MB);  // 16 MB  [4096][2048]
  float*  hs_f     = (float*) (ws + 104 * MB); // 4 MB   [8192][128]
  __bf16* hs_b     = (__bf16*)(ws + 108 * MB); // 2 MB
  float*  tt       = (float*) (ws + 110 * MB); // 32 MB  (resid1 out; reused as resid2 out)
  float*  yy       = (float*) (ws + 142 * MB); // 32 MB  (post-LN1 fp32)
  __bf16* yb       = (__bf16*)(ws + 174 * MB); // 16 MB
  __bf16* hb       = (__bf16*)(ws + 24 * MB);  // 64 MB, overlays xb/qkvb (dead by FFN1)

  hipMemsetAsync(hs_f, 0, (size_t)MM * AA * sizeof(float), stream);

  // weight prep
  transpose_qkv<<<dim3(2, 16, 24), 256, 0, stream>>>(Wq, Wk, Wv, WqkvT);
  build_qkv_bias<<<12, 256, 0, stream>>>(bq, bk, bv, qkv_bias);
  transpose_conv<<<dim3(16, 2), 256, 0, stream>>>(Wo, WoT, 128, 1024);
  transpose_conv<<<dim3(64, 16), 256, 0, stream>>>(W1, W1T, 1024, 4096);
  transpose_conv<<<dim3(16, 64), 256, 0, stream>>>(W2, W2T, 4096, 1024);
  conv_f32_bf16<<<8192, 256, 0, stream>>>(x, xb, MM * DD / 4);

  // QKV projection (writes q,k,v bf16 + V^T)
  gemm_bt<false, false, false, true, true><<<dim3(24, 64), 256, 0, stream>>>(
      xb, WqkvT, qkv_bias, nullptr, nullptr, qkvb, vTb, MM, 3072, 1024);

  // attention with head-sum
  attn_kernel<<<dim3(32, 8, 4), 256, 0, stream>>>(qkvb, vTb, hs_f);
  conv_f32_bf16<<<1024, 256, 0, stream>>>(hs_f, hs_b, MM * AA / 4);

  // out projection + residual(x)
  gemm_bt<false, true, true, false, false><<<dim3(8, 64), 256, 0, stream>>>(
      hs_b, WoT, bo, x, tt, nullptr, nullptr, MM, 1024, 128);
  ln_kernel<true><<<MM, 256, 0, stream>>>(tt, g1, be1, yy, yb);

  // FFN
  gemm_bt<true, false, false, true, false><<<dim3(32, 64), 256, 0, stream>>>(
      yb, W1T, bf1, nullptr, nullptr, hb, nullptr, MM, FF, 1024);
  gemm_bt<false, true, true, false, false><<<dim3(8, 64), 256, 0, stream>>>(
      hb, W2T, bf2, yy, tt, nullptr, nullptr, MM, DD, FF);
  ln_kernel<false><<<MM, 256, 0, stream>>>(tt, g2, be2, (float*)d_out, nullptr);
}

// Round 3
// 646.022 us; speedup vs baseline: 1.5125x; 1.5125x over previous
//
#include <hip/hip_runtime.h>
#include <hip/hip_bf16.h>
#include <stdint.h>

// Problem constants
#define DD 1024
#define AA 128
#define HH 8
#define FF 4096
#define BB 4
#define SS 2048
#define MM (BB*SS)      // 8192 tokens
#define EPSV 1e-5f

typedef __bf16 bf16x8 __attribute__((ext_vector_type(8)));
typedef __bf16 bf16x4 __attribute__((ext_vector_type(4)));
typedef float  f32x4  __attribute__((ext_vector_type(4)));

// ---------------- async global->LDS (16B per lane) ----------------
__device__ __forceinline__ void gload_lds16(const void* g, void* l) {
  __builtin_amdgcn_global_load_lds(
      (const __attribute__((address_space(1))) uint32_t*)(uintptr_t)g,
      (__attribute__((address_space(3))) uint32_t*)(uintptr_t)l, 16, 0, 0);
}

// ---------------- transpose + f32->bf16 convert: out[c][r] = in[r][c] ----------------
__global__ __launch_bounds__(256) void transpose_conv(const float* __restrict__ in,
                                                      __bf16* __restrict__ out,
                                                      int rows, int cols) {
  __shared__ float tile[64][65];
  const int r0 = blockIdx.y * 64, c0 = blockIdx.x * 64;
  for (int i = threadIdx.x; i < 4096; i += 256) {
    int r = i >> 6, c = i & 63;
    tile[r][c] = in[(long)(r0 + r) * cols + c0 + c];
  }
  __syncthreads();
  for (int i = threadIdx.x; i < 4096; i += 256) {
    int c = i >> 6, r = i & 63;
    out[(long)(c0 + c) * rows + r0 + r] = (__bf16)tile[r][c];
  }
}

// QKV weights: Wq/Wk/Wv are [H][D][A]; build WqkvT [3072][1024] (row n = p*1024+h*128+a, col d)
__global__ __launch_bounds__(256) void transpose_qkv(const float* __restrict__ Wq,
                                                     const float* __restrict__ Wk,
                                                     const float* __restrict__ Wv,
                                                     __bf16* __restrict__ out) {
  __shared__ float tile[64][65];
  const int z = blockIdx.z;
  const int p = z >> 3, h = z & 7;
  const float* in = ((p == 0) ? Wq : (p == 1) ? Wk : Wv) + (long)h * DD * AA;  // [D][A]
  __bf16* o = out + (long)(p * 1024 + h * 128) * DD;                           // [A][D]
  const int r0 = blockIdx.y * 64, c0 = blockIdx.x * 64;  // r over D, c over A
  for (int i = threadIdx.x; i < 4096; i += 256) {
    int r = i >> 6, c = i & 63;
    tile[r][c] = in[(long)(r0 + r) * AA + c0 + c];
  }
  __syncthreads();
  for (int i = threadIdx.x; i < 4096; i += 256) {
    int c = i >> 6, r = i & 63;
    o[(long)(c0 + c) * DD + r0 + r] = (__bf16)tile[r][c];
  }
}

__global__ void build_qkv_bias(const float* __restrict__ bq, const float* __restrict__ bk,
                               const float* __restrict__ bv, float* __restrict__ out) {
  int i = blockIdx.x * 256 + threadIdx.x;
  if (i < 3072) {
    const float* src = (i < 1024) ? bq : (i < 2048) ? bk : bv;
    out[i] = src[i & 1023];
  }
}

__global__ void conv_f32_bf16(const float* __restrict__ in, __bf16* __restrict__ out, int n4) {
  int i = blockIdx.x * 256 + threadIdx.x;
  if (i < n4) {
    float4 v = ((const float4*)in)[i];
    bf16x4 o = { (__bf16)v.x, (__bf16)v.y, (__bf16)v.z, (__bf16)v.w };
    ((bf16x4*)out)[i] = o;
  }
}

// ---------------- generic GEMM: C[M][N] = A[M][K](bf16) * Bt[N][K]^T + bias ----------------
template<bool RELU, bool RESID, bool OUTF, bool OUTB, bool WRVT>
__global__ __launch_bounds__(256) void gemm_bt(
    const __bf16* __restrict__ Ag, const __bf16* __restrict__ Bt,
    const float* __restrict__ bias, const float* __restrict__ resid,
    float* __restrict__ Cf, __bf16* __restrict__ Cb, __bf16* __restrict__ vTb,
    int M, int N, int K)
{
  __shared__ __bf16 As[128 * 32];
  __shared__ __bf16 Bs[128 * 32];
  const int t = threadIdx.x;
  const int w = t >> 6, l = t & 63;
  // XCD-aware swizzle (all grids are multiples of 8 blocks)
  const int gx = gridDim.x, nwg = gx * gridDim.y;
  int bid = blockIdx.y * gx + blockIdx.x;
  int swz = (bid & 7) * (nwg >> 3) + (bid >> 3);
  const int m0 = (swz / gx) * 128, n0 = (swz % gx) * 128;
  const int wr = w >> 1, wc = w & 1;
  const int lr = l & 15, lg = l >> 4;

  f32x4 acc[4][4] = {};

  const __bf16* gA = Ag + (long)(m0 + w * 32 + (l >> 2)) * K + (l & 3) * 8;
  const __bf16* gB = Bt + (long)(n0 + w * 32 + (l >> 2)) * K + (l & 3) * 8;
  __bf16* lA = &As[w * 1024];
  __bf16* lB = &Bs[w * 1024];

  for (int k0 = 0; k0 < K; k0 += 32) {
    gload_lds16(gA + k0, lA);
    gload_lds16(gA + (long)16 * K + k0, lA + 512);
    gload_lds16(gB + k0, lB);
    gload_lds16(gB + (long)16 * K + k0, lB + 512);
    __syncthreads();
    bf16x8 af[4], bfr[4];
#pragma unroll
    for (int mi = 0; mi < 4; mi++)
      af[mi] = *(const bf16x8*)&As[(wr * 64 + mi * 16 + lr) * 32 + lg * 8];
#pragma unroll
    for (int nj = 0; nj < 4; nj++)
      bfr[nj] = *(const bf16x8*)&Bs[(wc * 64 + nj * 16 + lr) * 32 + lg * 8];
#pragma unroll
    for (int mi = 0; mi < 4; mi++)
#pragma unroll
      for (int nj = 0; nj < 4; nj++)
        acc[mi][nj] = __builtin_amdgcn_mfma_f32_16x16x32_bf16(af[mi], bfr[nj], acc[mi][nj], 0, 0, 0);
    __syncthreads();
  }

#pragma unroll
  for (int mi = 0; mi < 4; mi++) {
    const int row0 = m0 + wr * 64 + mi * 16 + lg * 4;
#pragma unroll
    for (int nj = 0; nj < 4; nj++) {
      const int col = n0 + wc * 64 + nj * 16 + lr;
      const float bv = bias[col];
#pragma unroll
      for (int rg = 0; rg < 4; rg++) {
        const int row = row0 + rg;
        float v = acc[mi][nj][rg] + bv;
        if constexpr (RESID) v += resid[(long)row * N + col];
        if constexpr (RELU)  v = fmaxf(v, 0.f);
        if constexpr (OUTF)  Cf[(long)row * N + col] = v;
        if constexpr (OUTB)  Cb[(long)row * N + col] = (__bf16)v;
        if constexpr (WRVT) {
          if (col >= 2048) {  // V part -> also write V^T [b*8+h][a][s]
            int h = (col - 2048) >> 7, a = col & 127;
            int b = row >> 11, s = row & 2047;
            vTb[(((long)(b * 8 + h)) * 128 + a) * 2048 + s] = (__bf16)v;
          }
        }
      }
    }
  }
}

// ---------------- flash attention, heads -> per-head partial buffers ----------------
// grid (S/64, H, B); 4 waves, each owns 16 q-rows; KV tile = 128, staged in LDS.
// LDS tiles stored with T2 XOR swizzle: byte ^= ((row&7)<<4); gload source pre-swizzled.
__global__ __launch_bounds__(256) void attn_kernel(
    const __bf16* __restrict__ qkv,   // [8192][3072]  (q | k | v per head)
    const __bf16* __restrict__ vT,    // [B*H*128][2048]
    float* __restrict__ hsp)          // [H][8192][128] fp32 partials
{
  __shared__ __bf16 Ks[128 * 128];   // [kv][a], swizzled
  __shared__ __bf16 Vs[128 * 128];   // [a][kv], swizzled
  __shared__ __bf16 P_lds[4 * 16 * 128];  // per-wave [16][128], swizzled
  const int t = threadIdx.x, w = t >> 6, l = t & 63;
  const int lr = l & 15, lg = l >> 4;
  const int qt = blockIdx.x, h = blockIdx.y, b = blockIdx.z;
  const int q0 = qt * 64 + w * 16;
  const long rowbase = (long)b * SS + q0;
  const float inv_s = 0.0883883476483184f;  // 1/sqrt(128)

  // staging lane mapping: 4 rows/issue, lane -> row sr, 16B-chunk scg
  const int sr = l >> 4, scg = l & 15;

  // Q fragments: A[m=lr][k contiguous]
  bf16x8 qf[4];
  const __bf16* qptr = qkv + (rowbase + lr) * 3072 + h * 128;
#pragma unroll
  for (int ks = 0; ks < 4; ks++) qf[ks] = *(const bf16x8*)(qptr + ks * 32 + lg * 8);

  float m_[4] = { -1e30f, -1e30f, -1e30f, -1e30f };
  float l_[4] = {};
  f32x4 O[8] = {};

  __bf16* pl = &P_lds[w * 2048];
  const char* plc = (const char*)pl;
  const char* Ksc = (const char*)Ks;
  const char* Vsc = (const char*)Vs;
  const __bf16* kbase = qkv + (long)b * SS * 3072 + 1024 + h * 128;
  const __bf16* vbase = vT + ((long)(b * 8 + h) * 128) * 2048;

  // per-thread swizzled column bytes for reads: row-low-bits XOR
  int colx[4];
#pragma unroll
  for (int ks = 0; ks < 4; ks++) colx[ks] = ((ks << 6) | (lg << 4)) ^ ((lr & 7) << 4);

  for (int kt = 0; kt < SS / 128; kt++) {
    const int kv0 = kt * 128;
    // ---- stage K and V tiles (source pre-swizzled so linear LDS write = swizzled layout)
#pragma unroll
    for (int i = 0; i < 8; i++) {
      const int r = w * 32 + i * 4 + sr;           // tile row this lane covers
      const int so = (scg ^ (r & 7)) << 3;          // source element offset (16B granule swizzle)
      gload_lds16(kbase + (long)(kv0 + r) * 3072 + so, Ks + (w * 32 + i * 4) * 128);
      gload_lds16(vbase + (long)r * 2048 + kv0 + so, Vs + (w * 32 + i * 4) * 128);
    }
    __syncthreads();

    // ---- QK^T from LDS
    f32x4 sc[8] = {};
#pragma unroll
    for (int nj = 0; nj < 8; nj++) {
#pragma unroll
      for (int ks = 0; ks < 4; ks++) {
        bf16x8 kf = *(const bf16x8*)(Ksc + (nj * 16 + lr) * 256 + colx[ks]);
        sc[nj] = __builtin_amdgcn_mfma_f32_16x16x32_bf16(qf[ks], kf, sc[nj], 0, 0, 0);
      }
    }
    // ---- online softmax (rows: rg, 16 lanes per row-group)
    float rmax[4] = { -1e30f, -1e30f, -1e30f, -1e30f };
#pragma unroll
    for (int nj = 0; nj < 8; nj++)
#pragma unroll
      for (int rg = 0; rg < 4; rg++) {
        float v = sc[nj][rg] * inv_s;
        sc[nj][rg] = v;
        rmax[rg] = fmaxf(rmax[rg], v);
      }
#pragma unroll
    for (int rg = 0; rg < 4; rg++)
#pragma unroll
      for (int d = 1; d < 16; d <<= 1) rmax[rg] = fmaxf(rmax[rg], __shfl_xor(rmax[rg], d));

    float ss[4], rsum[4];
#pragma unroll
    for (int rg = 0; rg < 4; rg++) {
      float nm = fmaxf(m_[rg], rmax[rg]);
      ss[rg] = __expf(m_[rg] - nm);
      m_[rg] = nm;
      rsum[rg] = 0.f;
    }
#pragma unroll
    for (int nj = 0; nj < 8; nj++)
#pragma unroll
      for (int rg = 0; rg < 4; rg++) {
        float p = __expf(sc[nj][rg] - m_[rg]);
        sc[nj][rg] = p;
        rsum[rg] += p;
      }
#pragma unroll
    for (int rg = 0; rg < 4; rg++) {
#pragma unroll
      for (int d = 1; d < 16; d <<= 1) rsum[rg] += __shfl_xor(rsum[rg], d);
      l_[rg] = l_[rg] * ss[rg] + rsum[rg];
    }
    f32x4 sv = { ss[0], ss[1], ss[2], ss[3] };
#pragma unroll
    for (int aj = 0; aj < 8; aj++) O[aj] *= sv;

    // ---- P -> per-wave LDS (bf16, swizzled): row = lg*4+rg, col = nj*16+lr
#pragma unroll
    for (int nj = 0; nj < 8; nj++)
#pragma unroll
      for (int rg = 0; rg < 4; rg++) {
        const int prow = lg * 4 + rg;
        *(__bf16*)((char*)pl + prow * 256 + ((((nj * 16 + lr) << 1)) ^ ((prow & 7) << 4))) =
            (__bf16)sc[nj][rg];
      }
    asm volatile("s_waitcnt lgkmcnt(0)" ::: "memory");  // P writes visible intra-wave
    __builtin_amdgcn_sched_barrier(0);

    // ---- PV from LDS
#pragma unroll
    for (int ks = 0; ks < 4; ks++) {
      bf16x8 pa = *(const bf16x8*)(plc + lr * 256 + colx[ks]);
#pragma unroll
      for (int aj = 0; aj < 8; aj++) {
        bf16x8 vf = *(const bf16x8*)(Vsc + (aj * 16 + lr) * 256 + colx[ks]);
        O[aj] = __builtin_amdgcn_mfma_f32_16x16x32_bf16(pa, vf, O[aj], 0, 0, 0);
      }
    }
    __syncthreads();  // all reads of Ks/Vs done before next-tile overwrite
  }

  float invl[4];
#pragma unroll
  for (int rg = 0; rg < 4; rg++) invl[rg] = 1.f / l_[rg];
  float* ho = hsp + ((long)h * MM + rowbase) * AA;
#pragma unroll
  for (int aj = 0; aj < 8; aj++)
#pragma unroll
    for (int rg = 0; rg < 4; rg++)
      ho[(lg * 4 + rg) * AA + aj * 16 + lr] = O[aj][rg] * invl[rg];
}

// ---------------- sum 8 per-head partials -> bf16 ----------------
__global__ __launch_bounds__(256) void reduce_heads(const float* __restrict__ hsp,
                                                    __bf16* __restrict__ out) {
  const long i = (long)blockIdx.x * 256 + threadIdx.x;  // over MM*AA/4 float4s
  const float4* p = (const float4*)hsp;
  float4 s = p[i];
#pragma unroll
  for (int h = 1; h < 8; h++) {
    float4 v = p[i + (long)h * (MM * AA / 4)];
    s.x += v.x; s.y += v.y; s.z += v.z; s.w += v.w;
  }
  bf16x4 o = { (__bf16)s.x, (__bf16)s.y, (__bf16)s.z, (__bf16)s.w };
  ((bf16x4*)out)[i] = o;
}

// ---------------- LayerNorm over D=1024 (one block per row) ----------------
template<bool WB>
__global__ __launch_bounds__(256) void ln_kernel(
    const float* __restrict__ in, const float* __restrict__ g, const float* __restrict__ be,
    float* __restrict__ outf, __bf16* __restrict__ outb)
{
  const int row = blockIdx.x, t = threadIdx.x;
  const float4 xv = *(const float4*)(in + (long)row * DD + t * 4);
  float s = xv.x + xv.y + xv.z + xv.w;
  float s2 = xv.x * xv.x + xv.y * xv.y + xv.z * xv.z + xv.w * xv.w;
#pragma unroll
  for (int off = 32; off >= 1; off >>= 1) {
    s += __shfl_down(s, off);
    s2 += __shfl_down(s2, off);
  }
  __shared__ float sm[4], sm2[4];
  __shared__ float mu_s, rs_s;
  const int wid = t >> 6;
  if ((t & 63) == 0) { sm[wid] = s; sm2[wid] = s2; }
  __syncthreads();
  if (t == 0) {
    float S = sm[0] + sm[1] + sm[2] + sm[3];
    float S2 = sm2[0] + sm2[1] + sm2[2] + sm2[3];
    float mu = S * (1.f / 1024.f);
    float var = S2 * (1.f / 1024.f) - mu * mu;
    mu_s = mu;
    rs_s = rsqrtf(var + EPSV);
  }
  __syncthreads();
  const float mu = mu_s, rs = rs_s;
  const float4 gv = *(const float4*)(g + t * 4);
  const float4 bv = *(const float4*)(be + t * 4);
  float o0 = (xv.x - mu) * rs * gv.x + bv.x;
  float o1 = (xv.y - mu) * rs * gv.y + bv.y;
  float o2 = (xv.z - mu) * rs * gv.z + bv.z;
  float o3 = (xv.w - mu) * rs * gv.w + bv.w;
  float4 ov = { o0, o1, o2, o3 };
  *(float4*)(outf + (long)row * DD + t * 4) = ov;
  if constexpr (WB) {
    bf16x4 ob = { (__bf16)o0, (__bf16)o1, (__bf16)o2, (__bf16)o3 };
    *(bf16x4*)(outb + (long)row * DD + t * 4) = ob;
  }
}

// ---------------- launch ----------------
extern "C" void kernel_launch(void* const* d_in, const int* in_sizes, int n_in,
                              void* d_out, int out_size, void* d_ws, size_t ws_size,
                              hipStream_t stream) {
  const float* x    = (const float*)d_in[0];
  const float* Wq   = (const float*)d_in[1];
  const float* bq   = (const float*)d_in[2];
  const float* Wk   = (const float*)d_in[3];
  const float* bk   = (const float*)d_in[4];
  const float* Wv   = (const float*)d_in[5];
  const float* bv   = (const float*)d_in[6];
  const float* Wo   = (const float*)d_in[7];
  const float* bo   = (const float*)d_in[8];
  const float* g1   = (const float*)d_in[9];
  const float* be1  = (const float*)d_in[10];
  const float* g2   = (const float*)d_in[11];
  const float* be2  = (const float*)d_in[12];
  const float* W1   = (const float*)d_in[13];
  const float* bf1  = (const float*)d_in[14];
  const float* W2   = (const float*)d_in[15];
  const float* bf2  = (const float*)d_in[16];

  const size_t MB = 1ull << 20;
  char* ws = (char*)d_ws;
  __bf16* WqkvT    = (__bf16*)(ws + 0);         // 6 MB   [3072][1024]
  float*  qkv_bias = (float*) (ws + 6 * MB);    // 12 KB
  __bf16* WoT      = (__bf16*)(ws + 7 * MB);    // 256 KB [1024][128]
  __bf16* W1T      = (__bf16*)(ws + 8 * MB);    // 8 MB   [4096][1024]
  __bf16* W2T      = (__bf16*)(ws + 16 * MB);   // 8 MB   [1024][4096]
  __bf16* xb       = (__bf16*)(ws + 24 * MB);   // 16 MB  [8192][1024]
  __bf16* qkvb     = (__bf16*)(ws + 40 * MB);   // 48 MB  [8192][3072]
  __bf16* vTb      = (__bf16*)(ws + 88 * MB);   // 16 MB  [4096][2048]
  float*  hsp      = (float*) (ws + 104 * MB);  // 32 MB  [8][8192][128] fp32 partials
  __bf16* hs_b     = (__bf16*)(ws + 136 * MB);  // 2 MB
  float*  tt       = (float*) (ws + 104 * MB);  // 32 MB  (overlays hsp; hsp dead before out-proj)
  float*  yy       = (float*) (ws + 140 * MB);  // 32 MB  (post-LN1 fp32)
  __bf16* yb       = (__bf16*)(ws + 172 * MB);  // 16 MB
  __bf16* hb       = (__bf16*)(ws + 24 * MB);   // 64 MB, overlays xb/qkvb (dead by FFN1)

  // weight prep
  transpose_qkv<<<dim3(2, 16, 24), 256, 0, stream>>>(Wq, Wk, Wv, WqkvT);
  build_qkv_bias<<<12, 256, 0, stream>>>(bq, bk, bv, qkv_bias);
  transpose_conv<<<dim3(16, 2), 256, 0, stream>>>(Wo, WoT, 128, 1024);
  transpose_conv<<<dim3(64, 16), 256, 0, stream>>>(W1, W1T, 1024, 4096);
  transpose_conv<<<dim3(16, 64), 256, 0, stream>>>(W2, W2T, 4096, 1024);
  conv_f32_bf16<<<8192, 256, 0, stream>>>(x, xb, MM * DD / 4);

  // QKV projection (writes q,k,v bf16 + V^T)
  gemm_bt<false, false, false, true, true><<<dim3(24, 64), 256, 0, stream>>>(
      xb, WqkvT, qkv_bias, nullptr, nullptr, qkvb, vTb, MM, 3072, 1024);

  // attention -> per-head partials, then reduce
  attn_kernel<<<dim3(32, 8, 4), 256, 0, stream>>>(qkvb, vTb, hsp);
  reduce_heads<<<MM * AA / 4 / 256, 256, 0, stream>>>(hsp, hs_b);

  // out projection + residual(x)
  gemm_bt<false, true, true, false, false><<<dim3(8, 64), 256, 0, stream>>>(
      hs_b, WoT, bo, x, tt, nullptr, nullptr, MM, 1024, 128);
  ln_kernel<true><<<MM, 256, 0, stream>>>(tt, g1, be1, yy, yb);

  // FFN
  gemm_bt<true, false, false, true, false><<<dim3(32, 64), 256, 0, stream>>>(
      yb, W1T, bf1, nullptr, nullptr, hb, nullptr, MM, FF, 1024);
  gemm_bt<false, true, true, false, false><<<dim3(8, 64), 256, 0, stream>>>(
      hb, W2T, bf2, yy, tt, nullptr, nullptr, MM, DD, FF);
  ln_kernel<false><<<MM, 256, 0, stream>>>(tt, g2, be2, (float*)d_out, nullptr);
}